// Round 3
// baseline (340.462 us; speedup 1.0000x reference)
//
#include <hip/hip_runtime.h>
#include <hip/hip_fp16.h>
#include <math.h>

#define D 128
#define PADH 136  // LDS row stride in halves (272 B): 2-way bank alias only (free)

typedef __attribute__((ext_vector_type(8))) _Float16 half8;
typedef __attribute__((ext_vector_type(4))) float f32x4;

// ---------------- prep: WhT[l][n][k] = (half)Wl[k][n]  +  cnt zeroing ----------------

__global__ void prep_kernel(const float* __restrict__ W1, const float* __restrict__ W2,
                            const float* __restrict__ W3, __half* __restrict__ WhT,
                            int* __restrict__ cnt, int N) {
    int i = blockIdx.x * blockDim.x + threadIdx.x;
    if (i < 3 * D * D) {
        int l = i >> 14;
        int j = i & 16383;
        int n = j >> 7, k = j & 127;
        const float* W = (l == 0) ? W1 : (l == 1) ? W2 : W3;
        WhT[(size_t)i] = __float2half(W[(size_t)k * D + n]);
    }
    if (i < N) cnt[i] = 0;
}

// ---------------- graph build ----------------

__global__ void count_kernel(const int* __restrict__ dst, int* __restrict__ cnt, int E) {
    int e0 = (blockIdx.x * blockDim.x + threadIdx.x) * 8;
    if (e0 + 7 < E) {
        int4 da = *(const int4*)(dst + e0);
        int4 db = *(const int4*)(dst + e0 + 4);
        atomicAdd(&cnt[da.x], 1);
        atomicAdd(&cnt[da.y], 1);
        atomicAdd(&cnt[da.z], 1);
        atomicAdd(&cnt[da.w], 1);
        atomicAdd(&cnt[db.x], 1);
        atomicAdd(&cnt[db.y], 1);
        atomicAdd(&cnt[db.z], 1);
        atomicAdd(&cnt[db.w], 1);
    } else {
        for (int e = e0; e < E; ++e) atomicAdd(&cnt[dst[e]], 1);
    }
}

// single-block scan, one barrier pass: per-thread contiguous chunk, two vector sweeps.
// cnt[N] -> rowptr[N+1] (+ cursor copy); dinv[i] = rsqrt(cnt[i]+1)
__global__ __launch_bounds__(1024) void scan_kernel(const int* __restrict__ cnt,
                                                    int* __restrict__ rowptr,
                                                    int* __restrict__ cursor,
                                                    float* __restrict__ dinv,
                                                    int N) {
    __shared__ int wsum[16];
    int tid  = threadIdx.x;
    int lane = tid & 63;
    int wid  = tid >> 6;
    int C = ((N + 4095) / 4096) * 4;          // per-thread chunk, multiple of 4
    int start = tid * C;
    int end   = start + C; if (end > N) end = N;

    // sweep 1: local sum (independent int4 loads, all in flight)
    int local = 0;
    int i = start;
    for (; i + 3 < end; i += 4) {
        int4 v = *(const int4*)(cnt + i);
        local += v.x + v.y + v.z + v.w;
    }
    for (; i < end; ++i) local += cnt[i];

    // block scan of per-thread sums
    int sc = local;
    #pragma unroll
    for (int off = 1; off < 64; off <<= 1) {
        int t = __shfl_up(sc, off, 64);
        if (lane >= off) sc += t;
    }
    if (lane == 63) wsum[wid] = sc;
    __syncthreads();
    if (tid < 16) {
        int w = wsum[tid];
        #pragma unroll
        for (int off = 1; off < 16; off <<= 1) {
            int t = __shfl_up(w, off, 16);
            if (tid >= off) w += t;
        }
        wsum[tid] = w;
    }
    __syncthreads();
    int run = ((wid > 0) ? wsum[wid - 1] : 0) + (sc - local);

    // sweep 2: emit prefix (rowptr + cursor copy) + dinv (cnt now L2 hot)
    i = start;
    for (; i + 3 < end; i += 4) {
        int4 v = *(const int4*)(cnt + i);
        int4 rp;
        rp.x = run;
        rp.y = rp.x + v.x;
        rp.z = rp.y + v.y;
        rp.w = rp.z + v.z;
        run  = rp.w + v.w;
        *(int4*)(rowptr + i) = rp;
        *(int4*)(cursor + i) = rp;
        float4 dv;
        dv.x = rsqrtf((float)v.x + 1.0f);
        dv.y = rsqrtf((float)v.y + 1.0f);
        dv.z = rsqrtf((float)v.z + 1.0f);
        dv.w = rsqrtf((float)v.w + 1.0f);
        *(float4*)(dinv + i) = dv;
    }
    for (; i < end; ++i) {
        int v = cnt[i];
        rowptr[i] = run; cursor[i] = run; run += v;
        dinv[i] = rsqrtf((float)v + 1.0f);
    }
    if (tid == 0) rowptr[N] = wsum[15];
}

// ---------------- shared row-gather body ----------------
// returns a0 = self + sum_{col} g[col], lane holds positions (2*lane, 2*lane+1) as float2

#define GATHER(vv, cc) __half2 vv = ((const __half2*)(g + (size_t)(cc) * D))[lane]

__device__ __forceinline__ float2 gather_row(const __half* __restrict__ g,
                                             const int* __restrict__ rowptr,
                                             const int* __restrict__ col,
                                             int row, int lane) {
    int s = rowptr[row], e = rowptr[row + 1];
    __half2 hself = ((const __half2*)(g + (size_t)row * D))[lane];
    float2 a0 = __half22float2(hself);
    float2 a1 = make_float2(0.f, 0.f), a2 = make_float2(0.f, 0.f),
           a3 = make_float2(0.f, 0.f), a4 = make_float2(0.f, 0.f),
           a5 = make_float2(0.f, 0.f), a6 = make_float2(0.f, 0.f),
           a7 = make_float2(0.f, 0.f);

    for (int base = s; base < e; base += 64) {
        int idx = base + lane;
        int myc = (idx < e) ? col[idx] : 0;
        int nb  = min(64, e - base);
        int j = 0;
        for (; j + 16 <= nb; j += 16) {
            int c0 = __shfl(myc, j + 0),  c1 = __shfl(myc, j + 1);
            int c2 = __shfl(myc, j + 2),  c3 = __shfl(myc, j + 3);
            int c4 = __shfl(myc, j + 4),  c5 = __shfl(myc, j + 5);
            int c6 = __shfl(myc, j + 6),  c7 = __shfl(myc, j + 7);
            int c8 = __shfl(myc, j + 8),  c9 = __shfl(myc, j + 9);
            int cA = __shfl(myc, j + 10), cB = __shfl(myc, j + 11);
            int cC = __shfl(myc, j + 12), cD = __shfl(myc, j + 13);
            int cE = __shfl(myc, j + 14), cF = __shfl(myc, j + 15);
            GATHER(v0, c0); GATHER(v1, c1); GATHER(v2, c2); GATHER(v3, c3);
            GATHER(v4, c4); GATHER(v5, c5); GATHER(v6, c6); GATHER(v7, c7);
            GATHER(v8, c8); GATHER(v9, c9); GATHER(vA, cA); GATHER(vB, cB);
            GATHER(vC, cC); GATHER(vD, cD); GATHER(vE, cE); GATHER(vF, cF);
            a0.x += __low2float(v0); a0.y += __high2float(v0);
            a1.x += __low2float(v1); a1.y += __high2float(v1);
            a2.x += __low2float(v2); a2.y += __high2float(v2);
            a3.x += __low2float(v3); a3.y += __high2float(v3);
            a4.x += __low2float(v4); a4.y += __high2float(v4);
            a5.x += __low2float(v5); a5.y += __high2float(v5);
            a6.x += __low2float(v6); a6.y += __high2float(v6);
            a7.x += __low2float(v7); a7.y += __high2float(v7);
            a0.x += __low2float(v8); a0.y += __high2float(v8);
            a1.x += __low2float(v9); a1.y += __high2float(v9);
            a2.x += __low2float(vA); a2.y += __high2float(vA);
            a3.x += __low2float(vB); a3.y += __high2float(vB);
            a4.x += __low2float(vC); a4.y += __high2float(vC);
            a5.x += __low2float(vD); a5.y += __high2float(vD);
            a6.x += __low2float(vE); a6.y += __high2float(vE);
            a7.x += __low2float(vF); a7.y += __high2float(vF);
        }
        for (; j + 8 <= nb; j += 8) {
            int c0 = __shfl(myc, j + 0), c1 = __shfl(myc, j + 1);
            int c2 = __shfl(myc, j + 2), c3 = __shfl(myc, j + 3);
            int c4 = __shfl(myc, j + 4), c5 = __shfl(myc, j + 5);
            int c6 = __shfl(myc, j + 6), c7 = __shfl(myc, j + 7);
            GATHER(v0, c0); GATHER(v1, c1); GATHER(v2, c2); GATHER(v3, c3);
            GATHER(v4, c4); GATHER(v5, c5); GATHER(v6, c6); GATHER(v7, c7);
            a0.x += __low2float(v0); a0.y += __high2float(v0);
            a1.x += __low2float(v1); a1.y += __high2float(v1);
            a2.x += __low2float(v2); a2.y += __high2float(v2);
            a3.x += __low2float(v3); a3.y += __high2float(v3);
            a4.x += __low2float(v4); a4.y += __high2float(v4);
            a5.x += __low2float(v5); a5.y += __high2float(v5);
            a6.x += __low2float(v6); a6.y += __high2float(v6);
            a7.x += __low2float(v7); a7.y += __high2float(v7);
        }
        for (; j + 4 <= nb; j += 4) {
            int c0 = __shfl(myc, j + 0), c1 = __shfl(myc, j + 1);
            int c2 = __shfl(myc, j + 2), c3 = __shfl(myc, j + 3);
            GATHER(v0, c0); GATHER(v1, c1); GATHER(v2, c2); GATHER(v3, c3);
            a0.x += __low2float(v0); a0.y += __high2float(v0);
            a1.x += __low2float(v1); a1.y += __high2float(v1);
            a2.x += __low2float(v2); a2.y += __high2float(v2);
            a3.x += __low2float(v3); a3.y += __high2float(v3);
        }
        for (; j < nb; ++j) {
            int c = __shfl(myc, j);
            GATHER(v, c);
            a0.x += __low2float(v); a0.y += __high2float(v);
        }
    }
    a0.x += a1.x + a2.x + a3.x + a4.x + a5.x + a6.x + a7.x;
    a0.y += a1.y + a2.y + a3.y + a4.y + a5.y + a6.y + a7.y;
    return a0;
}

// ---------------- fill + gemm1 (fused by block range) ----------------
// fill: col[atomicAdd(&cursor[dst[e]],1)] = src[e]  (rank array eliminated)

__global__ __launch_bounds__(256) void fill_gemm1_kernel(
    const int* __restrict__ src, const int* __restrict__ dst,
    int* __restrict__ cursor, int* __restrict__ col, int E, int fill_blocks,
    const float* __restrict__ X, const __half* __restrict__ WhT,
    const float* __restrict__ dinv, __half* __restrict__ Y, int M) {
    int tid = threadIdx.x;
    if ((int)blockIdx.x < fill_blocks) {
        int e0 = (blockIdx.x * 256 + tid) * 8;
        if (e0 + 7 < E) {
            int4 da = *(const int4*)(dst + e0);
            int4 db = *(const int4*)(dst + e0 + 4);
            int4 sa = *(const int4*)(src + e0);
            int4 sb = *(const int4*)(src + e0 + 4);
            int p0 = atomicAdd(&cursor[da.x], 1);
            int p1 = atomicAdd(&cursor[da.y], 1);
            int p2 = atomicAdd(&cursor[da.z], 1);
            int p3 = atomicAdd(&cursor[da.w], 1);
            int p4 = atomicAdd(&cursor[db.x], 1);
            int p5 = atomicAdd(&cursor[db.y], 1);
            int p6 = atomicAdd(&cursor[db.z], 1);
            int p7 = atomicAdd(&cursor[db.w], 1);
            col[p0] = sa.x; col[p1] = sa.y; col[p2] = sa.z; col[p3] = sa.w;
            col[p4] = sb.x; col[p5] = sb.y; col[p6] = sb.z; col[p7] = sb.w;
        } else {
            for (int e = e0; e < E; ++e) {
                int p = atomicAdd(&cursor[dst[e]], 1);
                col[p] = src[e];
            }
        }
        return;
    }
    int bid  = blockIdx.x - fill_blocks;
    int wave = tid >> 6;
    int lane = tid & 63;
    int quad = lane >> 4;
    int l16  = lane & 15;
    int m0   = bid * 64 + wave * 16;
    if (m0 >= M) return;

    f32x4 acc[8];
    #pragma unroll
    for (int t = 0; t < 8; ++t) acc[t] = (f32x4)0.0f;

    const float* xrow = X + (size_t)(m0 + l16) * D;

    #pragma unroll
    for (int ks = 0; ks < 4; ++ks) {
        int k0 = ks * 32 + quad * 8;
        float4 x0 = *(const float4*)(xrow + k0);
        float4 x1 = *(const float4*)(xrow + k0 + 4);
        half8 a;
        a[0] = (_Float16)x0.x; a[1] = (_Float16)x0.y;
        a[2] = (_Float16)x0.z; a[3] = (_Float16)x0.w;
        a[4] = (_Float16)x1.x; a[5] = (_Float16)x1.y;
        a[6] = (_Float16)x1.z; a[7] = (_Float16)x1.w;
        #pragma unroll
        for (int t = 0; t < 8; ++t) {
            half8 b = *(const half8*)(WhT + (size_t)(t * 16 + l16) * D + k0);
            acc[t] = __builtin_amdgcn_mfma_f32_16x16x32_f16(a, b, acc[t], 0, 0, 0);
        }
    }

    float4 dv = *(const float4*)(dinv + m0 + quad * 4);
    float dvs[4] = {dv.x, dv.y, dv.z, dv.w};
    #pragma unroll
    for (int t = 0; t < 8; ++t) {
        #pragma unroll
        for (int r = 0; r < 4; ++r) {
            int grow = m0 + quad * 4 + r;
            Y[(size_t)grow * D + t * 16 + l16] = __float2half(acc[t][r] * dvs[r]);
        }
    }
}

// ---------------- fused aggregate + GEMM (layers 2,3) ----------------
// 512 threads (8 waves), 16 rows/block, 2 rows/wave gather.
// 48 VGPR / 4.4 KB LDS -> 4 blocks/CU = 32 waves/CU resident (vs 12 in R2):
// ~2.7x more outstanding gather lines per CU.
// GEMM phase: wave w computes all 16 rows x col-tile w (16 cols), 4 MFMAs.

__global__ __launch_bounds__(512) void agg_gemm_kernel(
    const __half* __restrict__ ysIn, const int* __restrict__ rowptr,
    const int* __restrict__ col, const float* __restrict__ dinv,
    const float* __restrict__ bias, const __half* __restrict__ WhT,
    __half* __restrict__ ysOut, int M) {
    __shared__ __half lds_h[16 * PADH];
    int tid  = threadIdx.x;
    int wave = tid >> 6;
    int lane = tid & 63;
    int rbase = blockIdx.x * 16;

    float2 bb = ((const float2*)bias)[lane];
    #pragma unroll
    for (int t = 0; t < 2; ++t) {
        int r   = wave * 2 + t;
        int row = rbase + r;
        if (row < M) {
            float2 a = gather_row(ysIn, rowptr, col, row, lane);
            float dv = dinv[row];
            float rx = bb.x + dv * a.x;
            float ry = bb.y + dv * a.y;
            __half2 hv = __floats2half2_rn(fmaxf(rx, 0.f), fmaxf(ry, 0.f));
            ((__half2*)(lds_h + (size_t)r * PADH))[lane] = hv;
        }
    }
    __syncthreads();

    if (rbase >= M) return;
    int quad = lane >> 4;
    int l16  = lane & 15;

    f32x4 acc = (f32x4)0.0f;
    const __half* arow = lds_h + (size_t)l16 * PADH;

    #pragma unroll
    for (int ks = 0; ks < 4; ++ks) {
        int k0 = ks * 32 + quad * 8;
        half8 a = *(const half8*)(arow + k0);
        half8 b = *(const half8*)(WhT + (size_t)(wave * 16 + l16) * D + k0);
        acc = __builtin_amdgcn_mfma_f32_16x16x32_f16(a, b, acc, 0, 0, 0);
    }

    #pragma unroll
    for (int r = 0; r < 4; ++r) {
        int grow = rbase + quad * 4 + r;
        if (grow < M) {
            float dvr = dinv[grow];
            ysOut[(size_t)grow * D + wave * 16 + l16] = __float2half(acc[r] * dvr);
        }
    }
}

// ---------------- final aggregate: out = b3 + dinv*(self+neighbors), fp32 ----------------

__global__ __launch_bounds__(256) void agg_final_kernel(
    const __half* __restrict__ ys, const int* __restrict__ rowptr,
    const int* __restrict__ col, const float* __restrict__ dinv,
    const float* __restrict__ b, float* __restrict__ out, int N) {
    int gwave = (blockIdx.x * blockDim.x + threadIdx.x) >> 6;
    int lane  = threadIdx.x & 63;
    if (gwave >= N) return;
    float2 a  = gather_row(ys, rowptr, col, gwave, lane);
    float dv  = dinv[gwave];
    float2 bb = ((const float2*)b)[lane];
    ((float2*)(out + (size_t)gwave * D))[lane] = make_float2(bb.x + dv * a.x, bb.y + dv * a.y);
}

// ---------------- launch ----------------

extern "C" void kernel_launch(void* const* d_in, const int* in_sizes, int n_in,
                              void* d_out, int out_size, void* d_ws, size_t ws_size,
                              hipStream_t stream) {
    const float* x   = (const float*)d_in[0];
    const int*   ei  = (const int*)d_in[1];
    const float* W1  = (const float*)d_in[2];
    const float* b1  = (const float*)d_in[3];
    const float* W2  = (const float*)d_in[4];
    const float* b2  = (const float*)d_in[5];
    const float* W3  = (const float*)d_in[6];
    const float* b3  = (const float*)d_in[7];
    float* out = (float*)d_out;

    const int N = in_sizes[0] / D;
    const int E = in_sizes[1] / 2;
    const int* src = ei;
    const int* dst = ei + E;

    char* ws = (char*)d_ws;
    size_t off = 0;
    auto alloc = [&](size_t bytes) {
        void* p = ws + off;
        off = (off + bytes + 255) & ~(size_t)255;
        return p;
    };
    __half* ys    = (__half*)alloc((size_t)N * D * sizeof(__half));
    __half* hs    = (__half*)alloc((size_t)N * D * sizeof(__half));
    int*   cnt    = (int*)alloc((size_t)N * sizeof(int));
    int*   rowptr = (int*)alloc((size_t)(N + 1) * sizeof(int));
    int*   cursor = (int*)alloc((size_t)N * sizeof(int));
    float* dinv   = (float*)alloc((size_t)N * sizeof(float));
    int*   col    = (int*)alloc((size_t)E * sizeof(int));
    __half* WhT   = (__half*)alloc((size_t)3 * D * D * sizeof(__half));
    (void)ws_size; (void)n_in; (void)out_size;

    // 1. prep: W transpose/convert + cnt zero
    int prep_threads = (3 * D * D > N) ? 3 * D * D : N;
    prep_kernel<<<(prep_threads + 255) / 256, 256, 0, stream>>>(W1, W2, W3, WhT, cnt, N);

    // 2-3. count + scan (scan also emits cursor copy)
    const int egrid = ((E + 7) / 8 + 255) / 256;
    count_kernel<<<egrid, 256, 0, stream>>>(dst, cnt, E);
    scan_kernel<<<1, 1024, 0, stream>>>(cnt, rowptr, cursor, dinv, N);

    // 4. fill + gemm1 fused
    const int gemm1_grid = (N + 63) / 64;
    fill_gemm1_kernel<<<egrid + gemm1_grid, 256, 0, stream>>>(
        src, dst, cursor, col, E, egrid, x, WhT, dinv, ys, N);

    // 5-6. fused aggregate+GEMM, 8 waves x 2 rows: layer-2 (ys -> hs), layer-3 (hs -> ys)
    const int agg_gemm_grid = (N + 15) / 16;
    agg_gemm_kernel<<<agg_gemm_grid, 512, 0, stream>>>(ys, rowptr, col, dinv, b1, WhT + 16384, hs, N);
    agg_gemm_kernel<<<agg_gemm_grid, 512, 0, stream>>>(hs, rowptr, col, dinv, b2, WhT + 32768, ys, N);

    // 7. final aggregate -> fp32 out
    const int agg_grid = (N * 64 + 255) / 256;
    agg_final_kernel<<<agg_grid, 256, 0, stream>>>(ys, rowptr, col, dinv, b3, out, N);
}

// Round 4
// 294.232 us; speedup vs baseline: 1.1571x; 1.1571x over previous
//
#include <hip/hip_runtime.h>
#include <hip/hip_fp16.h>
#include <math.h>

#define D 128
#define PADH 136  // LDS row stride in halves (272 B): 2-way bank alias only (free)

typedef __attribute__((ext_vector_type(8))) _Float16 half8;
typedef __attribute__((ext_vector_type(4))) _Float16 half4v;
typedef __attribute__((ext_vector_type(4))) float f32x4;

// ---------------- prep: WhT[l][n][k] = (half)Wl[k][n]  +  cnt zeroing ----------------

__global__ void prep_kernel(const float* __restrict__ W1, const float* __restrict__ W2,
                            const float* __restrict__ W3, __half* __restrict__ WhT,
                            int* __restrict__ cnt, int N) {
    int i = blockIdx.x * blockDim.x + threadIdx.x;
    if (i < 3 * D * D) {
        int l = i >> 14;
        int j = i & 16383;
        int n = j >> 7, k = j & 127;
        const float* W = (l == 0) ? W1 : (l == 1) ? W2 : W3;
        WhT[(size_t)i] = __float2half(W[(size_t)k * D + n]);
    }
    if (i < N) cnt[i] = 0;
}

// ---------------- graph build ----------------

// rank[e] = arrival order of edge e within its dst bucket; cnt[d] = in-degree
__global__ void count_rank_kernel(const int* __restrict__ dst, int* __restrict__ cnt,
                                  int* __restrict__ rank, int E) {
    int e0 = (blockIdx.x * blockDim.x + threadIdx.x) * 8;
    if (e0 + 7 < E) {
        int4 da = *(const int4*)(dst + e0);
        int4 db = *(const int4*)(dst + e0 + 4);
        int4 ra, rb;
        ra.x = atomicAdd(&cnt[da.x], 1);
        ra.y = atomicAdd(&cnt[da.y], 1);
        ra.z = atomicAdd(&cnt[da.z], 1);
        ra.w = atomicAdd(&cnt[da.w], 1);
        rb.x = atomicAdd(&cnt[db.x], 1);
        rb.y = atomicAdd(&cnt[db.y], 1);
        rb.z = atomicAdd(&cnt[db.z], 1);
        rb.w = atomicAdd(&cnt[db.w], 1);
        *(int4*)(rank + e0)     = ra;
        *(int4*)(rank + e0 + 4) = rb;
    } else {
        for (int e = e0; e < E; ++e) rank[e] = atomicAdd(&cnt[dst[e]], 1);
    }
}

// single-block scan, one barrier pass: per-thread contiguous chunk, two vector sweeps.
// cnt[N] -> rowptr[N+1]; dinv[i] = rsqrt(cnt[i]+1)
__global__ __launch_bounds__(1024) void scan_kernel(const int* __restrict__ cnt,
                                                    int* __restrict__ rowptr,
                                                    float* __restrict__ dinv,
                                                    int N) {
    __shared__ int wsum[16];
    int tid  = threadIdx.x;
    int lane = tid & 63;
    int wid  = tid >> 6;
    int C = ((N + 4095) / 4096) * 4;          // per-thread chunk, multiple of 4
    int start = tid * C;
    int end   = start + C; if (end > N) end = N;

    // sweep 1: local sum (independent int4 loads, all in flight)
    int local = 0;
    int i = start;
    for (; i + 3 < end; i += 4) {
        int4 v = *(const int4*)(cnt + i);
        local += v.x + v.y + v.z + v.w;
    }
    for (; i < end; ++i) local += cnt[i];

    // block scan of per-thread sums
    int sc = local;
    #pragma unroll
    for (int off = 1; off < 64; off <<= 1) {
        int t = __shfl_up(sc, off, 64);
        if (lane >= off) sc += t;
    }
    if (lane == 63) wsum[wid] = sc;
    __syncthreads();
    if (tid < 16) {
        int w = wsum[tid];
        #pragma unroll
        for (int off = 1; off < 16; off <<= 1) {
            int t = __shfl_up(w, off, 16);
            if (tid >= off) w += t;
        }
        wsum[tid] = w;
    }
    __syncthreads();
    int run = ((wid > 0) ? wsum[wid - 1] : 0) + (sc - local);

    // sweep 2: emit prefix + dinv (cnt now L2 hot)
    i = start;
    for (; i + 3 < end; i += 4) {
        int4 v = *(const int4*)(cnt + i);
        int4 rp;
        rp.x = run;
        rp.y = rp.x + v.x;
        rp.z = rp.y + v.y;
        rp.w = rp.z + v.z;
        run  = rp.w + v.w;
        *(int4*)(rowptr + i) = rp;
        float4 dv;
        dv.x = rsqrtf((float)v.x + 1.0f);
        dv.y = rsqrtf((float)v.y + 1.0f);
        dv.z = rsqrtf((float)v.z + 1.0f);
        dv.w = rsqrtf((float)v.w + 1.0f);
        *(float4*)(dinv + i) = dv;
    }
    for (; i < end; ++i) {
        int v = cnt[i];
        rowptr[i] = run; run += v;
        dinv[i] = rsqrtf((float)v + 1.0f);
    }
    if (tid == 0) rowptr[N] = wsum[15];
}

// ---------------- dual-row gather ----------------
// Lanes 0-31 process row r0, lanes 32-63 row r1; each lane holds 4 halves (8B).
// One gather instruction fetches BOTH rows' 256B lines; one shfl broadcasts
// indices for both halves. Returns self+neighbor sum (4 floats per lane).

__device__ __forceinline__ float4 gather2(const __half* __restrict__ g,
                                          const int* __restrict__ rowptr,
                                          const int* __restrict__ col,
                                          int r0, int r1, int lane) {
    int half = lane >> 5;
    int l32  = lane & 31;
    int hb   = half << 5;
    int row  = half ? r1 : r0;
    int s = rowptr[row], e = rowptr[row + 1];

    half4v hs = ((const half4v*)(g + (size_t)row * D))[l32];
    float4 A = make_float4((float)hs[0], (float)hs[1], (float)hs[2], (float)hs[3]);
    float4 B = make_float4(0.f, 0.f, 0.f, 0.f);

    for (int base = s; base < e; base += 32) {
        int idx = base + l32;
        int myc = (idx < e) ? col[idx] : 0;
        int nb  = min(32, e - base);
        int j = 0;
        for (; j + 8 <= nb; j += 8) {
            int c0 = __shfl(myc, hb + j + 0), c1 = __shfl(myc, hb + j + 1);
            int c2 = __shfl(myc, hb + j + 2), c3 = __shfl(myc, hb + j + 3);
            int c4 = __shfl(myc, hb + j + 4), c5 = __shfl(myc, hb + j + 5);
            int c6 = __shfl(myc, hb + j + 6), c7 = __shfl(myc, hb + j + 7);
            half4v v0 = ((const half4v*)(g + (size_t)c0 * D))[l32];
            half4v v1 = ((const half4v*)(g + (size_t)c1 * D))[l32];
            half4v v2 = ((const half4v*)(g + (size_t)c2 * D))[l32];
            half4v v3 = ((const half4v*)(g + (size_t)c3 * D))[l32];
            half4v v4 = ((const half4v*)(g + (size_t)c4 * D))[l32];
            half4v v5 = ((const half4v*)(g + (size_t)c5 * D))[l32];
            half4v v6 = ((const half4v*)(g + (size_t)c6 * D))[l32];
            half4v v7 = ((const half4v*)(g + (size_t)c7 * D))[l32];
            A.x += (float)v0[0]; A.y += (float)v0[1]; A.z += (float)v0[2]; A.w += (float)v0[3];
            B.x += (float)v1[0]; B.y += (float)v1[1]; B.z += (float)v1[2]; B.w += (float)v1[3];
            A.x += (float)v2[0]; A.y += (float)v2[1]; A.z += (float)v2[2]; A.w += (float)v2[3];
            B.x += (float)v3[0]; B.y += (float)v3[1]; B.z += (float)v3[2]; B.w += (float)v3[3];
            A.x += (float)v4[0]; A.y += (float)v4[1]; A.z += (float)v4[2]; A.w += (float)v4[3];
            B.x += (float)v5[0]; B.y += (float)v5[1]; B.z += (float)v5[2]; B.w += (float)v5[3];
            A.x += (float)v6[0]; A.y += (float)v6[1]; A.z += (float)v6[2]; A.w += (float)v6[3];
            B.x += (float)v7[0]; B.y += (float)v7[1]; B.z += (float)v7[2]; B.w += (float)v7[3];
        }
        for (; j + 4 <= nb; j += 4) {
            int c0 = __shfl(myc, hb + j + 0), c1 = __shfl(myc, hb + j + 1);
            int c2 = __shfl(myc, hb + j + 2), c3 = __shfl(myc, hb + j + 3);
            half4v v0 = ((const half4v*)(g + (size_t)c0 * D))[l32];
            half4v v1 = ((const half4v*)(g + (size_t)c1 * D))[l32];
            half4v v2 = ((const half4v*)(g + (size_t)c2 * D))[l32];
            half4v v3 = ((const half4v*)(g + (size_t)c3 * D))[l32];
            A.x += (float)v0[0]; A.y += (float)v0[1]; A.z += (float)v0[2]; A.w += (float)v0[3];
            B.x += (float)v1[0]; B.y += (float)v1[1]; B.z += (float)v1[2]; B.w += (float)v1[3];
            A.x += (float)v2[0]; A.y += (float)v2[1]; A.z += (float)v2[2]; A.w += (float)v2[3];
            B.x += (float)v3[0]; B.y += (float)v3[1]; B.z += (float)v3[2]; B.w += (float)v3[3];
        }
        for (; j < nb; ++j) {
            int c = __shfl(myc, hb + j);
            half4v v = ((const half4v*)(g + (size_t)c * D))[l32];
            A.x += (float)v[0]; A.y += (float)v[1]; A.z += (float)v[2]; A.w += (float)v[3];
        }
    }
    A.x += B.x; A.y += B.y; A.z += B.z; A.w += B.w;
    return A;
}

// ---------------- fill + gemm1 (fused by block range) ----------------
// fill: col[rowptr[dst[e]] + rank[e]] = src[e]   (rank-based, no atomics)

__global__ __launch_bounds__(256) void fill_gemm1_kernel(
    const int* __restrict__ src, const int* __restrict__ dst,
    const int* __restrict__ rank, const int* __restrict__ rowptr,
    int* __restrict__ col, int E, int fill_blocks,
    const float* __restrict__ X, const __half* __restrict__ WhT,
    const float* __restrict__ dinv, __half* __restrict__ Y, int M) {
    int tid = threadIdx.x;
    if ((int)blockIdx.x < fill_blocks) {
        int e0 = (blockIdx.x * 256 + tid) * 8;
        if (e0 + 7 < E) {
            int4 da = *(const int4*)(dst + e0);
            int4 db = *(const int4*)(dst + e0 + 4);
            int4 ra = *(const int4*)(rank + e0);
            int4 rb = *(const int4*)(rank + e0 + 4);
            int4 sa = *(const int4*)(src + e0);
            int4 sb = *(const int4*)(src + e0 + 4);
            int p0 = rowptr[da.x] + ra.x;
            int p1 = rowptr[da.y] + ra.y;
            int p2 = rowptr[da.z] + ra.z;
            int p3 = rowptr[da.w] + ra.w;
            int p4 = rowptr[db.x] + rb.x;
            int p5 = rowptr[db.y] + rb.y;
            int p6 = rowptr[db.z] + rb.z;
            int p7 = rowptr[db.w] + rb.w;
            col[p0] = sa.x; col[p1] = sa.y; col[p2] = sa.z; col[p3] = sa.w;
            col[p4] = sb.x; col[p5] = sb.y; col[p6] = sb.z; col[p7] = sb.w;
        } else {
            for (int e = e0; e < E; ++e) col[rowptr[dst[e]] + rank[e]] = src[e];
        }
        return;
    }
    int bid  = blockIdx.x - fill_blocks;
    int wave = tid >> 6;
    int lane = tid & 63;
    int quad = lane >> 4;
    int l16  = lane & 15;
    int m0   = bid * 64 + wave * 16;
    if (m0 >= M) return;

    f32x4 acc[8];
    #pragma unroll
    for (int t = 0; t < 8; ++t) acc[t] = (f32x4)0.0f;

    const float* xrow = X + (size_t)(m0 + l16) * D;

    #pragma unroll
    for (int ks = 0; ks < 4; ++ks) {
        int k0 = ks * 32 + quad * 8;
        float4 x0 = *(const float4*)(xrow + k0);
        float4 x1 = *(const float4*)(xrow + k0 + 4);
        half8 a;
        a[0] = (_Float16)x0.x; a[1] = (_Float16)x0.y;
        a[2] = (_Float16)x0.z; a[3] = (_Float16)x0.w;
        a[4] = (_Float16)x1.x; a[5] = (_Float16)x1.y;
        a[6] = (_Float16)x1.z; a[7] = (_Float16)x1.w;
        #pragma unroll
        for (int t = 0; t < 8; ++t) {
            half8 b = *(const half8*)(WhT + (size_t)(t * 16 + l16) * D + k0);
            acc[t] = __builtin_amdgcn_mfma_f32_16x16x32_f16(a, b, acc[t], 0, 0, 0);
        }
    }

    float4 dv = *(const float4*)(dinv + m0 + quad * 4);
    float dvs[4] = {dv.x, dv.y, dv.z, dv.w};
    #pragma unroll
    for (int t = 0; t < 8; ++t) {
        #pragma unroll
        for (int r = 0; r < 4; ++r) {
            int grow = m0 + quad * 4 + r;
            Y[(size_t)grow * D + t * 16 + l16] = __float2half(acc[t][r] * dvs[r]);
        }
    }
}

// ---------------- fused aggregate + GEMM (layers 2,3) ----------------
// R2 geometry (256 threads / 4 waves / 16 rows), dual-row gather:
// each wave aggregates its 4 rows as 2 dual-gathers (half latency, 2x MLP vs R2).
// GEMM phase: wave computes all 16 rows x 32-col tile (R2 proven path).

__global__ __launch_bounds__(256) void agg_gemm_kernel(
    const __half* __restrict__ ysIn, const int* __restrict__ rowptr,
    const int* __restrict__ col, const float* __restrict__ dinv,
    const float* __restrict__ bias, const __half* __restrict__ WhT,
    __half* __restrict__ ysOut, int M) {
    __shared__ __half lds_h[16 * PADH];
    int tid  = threadIdx.x;
    int wave = tid >> 6;
    int lane = tid & 63;
    int half = lane >> 5;
    int l32  = lane & 31;
    int rbase = blockIdx.x * 16;

    float4 bb = ((const float4*)bias)[l32];
    #pragma unroll
    for (int t = 0; t < 2; ++t) {
        int lr0 = wave * 4 + t * 2;          // local rows lr0, lr0+1
        int row0 = rbase + lr0;
        int row1 = row0 + 1;
        int c0 = min(row0, M - 1);
        int c1 = min(row1, M - 1);
        float4 a = gather2(ysIn, rowptr, col, c0, c1, lane);
        int myrow = half ? c1 : c0;
        float dv = dinv[myrow];
        half4v hv;
        hv[0] = (_Float16)fmaxf(bb.x + dv * a.x, 0.f);
        hv[1] = (_Float16)fmaxf(bb.y + dv * a.y, 0.f);
        hv[2] = (_Float16)fmaxf(bb.z + dv * a.z, 0.f);
        hv[3] = (_Float16)fmaxf(bb.w + dv * a.w, 0.f);
        ((half4v*)(lds_h + (size_t)(lr0 + half) * PADH))[l32] = hv;
    }
    __syncthreads();

    if (rbase >= M) return;
    int quad = lane >> 4;
    int l16  = lane & 15;
    int t0   = wave * 2;

    f32x4 acc0 = (f32x4)0.0f, acc1 = (f32x4)0.0f;
    const __half* arow = lds_h + (size_t)l16 * PADH;

    #pragma unroll
    for (int ks = 0; ks < 4; ++ks) {
        int k0 = ks * 32 + quad * 8;
        half8 a  = *(const half8*)(arow + k0);
        half8 b0 = *(const half8*)(WhT + (size_t)((t0 + 0) * 16 + l16) * D + k0);
        half8 b1 = *(const half8*)(WhT + (size_t)((t0 + 1) * 16 + l16) * D + k0);
        acc0 = __builtin_amdgcn_mfma_f32_16x16x32_f16(a, b0, acc0, 0, 0, 0);
        acc1 = __builtin_amdgcn_mfma_f32_16x16x32_f16(a, b1, acc1, 0, 0, 0);
    }

    #pragma unroll
    for (int r = 0; r < 4; ++r) {
        int grow = rbase + quad * 4 + r;
        if (grow < M) {
            float dvr = dinv[grow];
            ysOut[(size_t)grow * D + (t0 + 0) * 16 + l16] = __float2half(acc0[r] * dvr);
            ysOut[(size_t)grow * D + (t0 + 1) * 16 + l16] = __float2half(acc1[r] * dvr);
        }
    }
}

// ---------------- final aggregate: out = b3 + dinv*(self+neighbors), fp32 ----------------
// dual-row: each wave handles 2 rows (half-wave each).

__global__ __launch_bounds__(256) void agg_final_kernel(
    const __half* __restrict__ ys, const int* __restrict__ rowptr,
    const int* __restrict__ col, const float* __restrict__ dinv,
    const float* __restrict__ b, float* __restrict__ out, int N) {
    int gwave = (blockIdx.x * blockDim.x + threadIdx.x) >> 6;
    int lane  = threadIdx.x & 63;
    int half  = lane >> 5;
    int l32   = lane & 31;
    int row0  = gwave * 2;
    if (row0 >= N) return;
    int row1  = row0 + 1;
    int c1    = min(row1, N - 1);

    float4 a = gather2(ys, rowptr, col, row0, c1, lane);
    int myrow = half ? c1 : row0;
    int orow  = row0 + half;
    if (orow < N) {
        float dv  = dinv[myrow];
        float4 bb = ((const float4*)b)[l32];
        float4 r;
        r.x = bb.x + dv * a.x;
        r.y = bb.y + dv * a.y;
        r.z = bb.z + dv * a.z;
        r.w = bb.w + dv * a.w;
        ((float4*)(out + (size_t)orow * D))[l32] = r;
    }
}

// ---------------- launch ----------------

extern "C" void kernel_launch(void* const* d_in, const int* in_sizes, int n_in,
                              void* d_out, int out_size, void* d_ws, size_t ws_size,
                              hipStream_t stream) {
    const float* x   = (const float*)d_in[0];
    const int*   ei  = (const int*)d_in[1];
    const float* W1  = (const float*)d_in[2];
    const float* b1  = (const float*)d_in[3];
    const float* W2  = (const float*)d_in[4];
    const float* b2  = (const float*)d_in[5];
    const float* W3  = (const float*)d_in[6];
    const float* b3  = (const float*)d_in[7];
    float* out = (float*)d_out;

    const int N = in_sizes[0] / D;
    const int E = in_sizes[1] / 2;
    const int* src = ei;
    const int* dst = ei + E;

    char* ws = (char*)d_ws;
    size_t off = 0;
    auto alloc = [&](size_t bytes) {
        void* p = ws + off;
        off = (off + bytes + 255) & ~(size_t)255;
        return p;
    };
    __half* ys    = (__half*)alloc((size_t)N * D * sizeof(__half));
    __half* hs    = (__half*)alloc((size_t)N * D * sizeof(__half));
    int*   cnt    = (int*)alloc((size_t)N * sizeof(int));
    int*   rowptr = (int*)alloc((size_t)(N + 1) * sizeof(int));
    float* dinv   = (float*)alloc((size_t)N * sizeof(float));
    int*   rank   = (int*)alloc((size_t)E * sizeof(int));
    int*   col    = (int*)alloc((size_t)E * sizeof(int));
    __half* WhT   = (__half*)alloc((size_t)3 * D * D * sizeof(__half));
    (void)ws_size; (void)n_in; (void)out_size;

    // 1. prep: W transpose/convert + cnt zero
    int prep_threads = (3 * D * D > N) ? 3 * D * D : N;
    prep_kernel<<<(prep_threads + 255) / 256, 256, 0, stream>>>(W1, W2, W3, WhT, cnt, N);

    // 2-3. count+rank, scan
    const int egrid = ((E + 7) / 8 + 255) / 256;
    count_rank_kernel<<<egrid, 256, 0, stream>>>(dst, cnt, rank, E);
    scan_kernel<<<1, 1024, 0, stream>>>(cnt, rowptr, dinv, N);

    // 4. fill + gemm1 fused
    const int gemm1_grid = (N + 63) / 64;
    fill_gemm1_kernel<<<egrid + gemm1_grid, 256, 0, stream>>>(
        src, dst, rank, rowptr, col, E, egrid, x, WhT, dinv, ys, N);

    // 5-6. fused aggregate+GEMM with dual-row gather: layer-2 (ys->hs), layer-3 (hs->ys)
    const int agg_gemm_grid = (N + 15) / 16;
    agg_gemm_kernel<<<agg_gemm_grid, 256, 0, stream>>>(ys, rowptr, col, dinv, b1, WhT + 16384, hs, N);
    agg_gemm_kernel<<<agg_gemm_grid, 256, 0, stream>>>(hs, rowptr, col, dinv, b2, WhT + 32768, ys, N);

    // 7. final aggregate (dual-row) -> fp32 out
    const int aggf_grid = ((N + 1) / 2 * 64 + 255) / 256;
    agg_final_kernel<<<aggf_grid, 256, 0, stream>>>(ys, rowptr, col, dinv, b3, out, N);
}